// Round 4
// baseline (489.076 us; speedup 1.0000x reference)
//
#include <hip/hip_runtime.h>
#include <stdint.h>

#define B_DIM 4096
#define DIN   2048
#define UNITS 2048
#define KDIM  4096   // DIN + UNITS
#define BK    64     // k per LDS tile
#define BM    256
#define BN    256    // 4 gates x 64 units

using s8v = __attribute__((ext_vector_type(8))) short;   // 8 x bf16 (4 VGPRs)
using f4v = __attribute__((ext_vector_type(4))) float;   // 4 x f32 acc

__device__ __forceinline__ unsigned short f2bf(float f) {
    union { float f; unsigned u; } v; v.f = f;
    unsigned u = v.u;
    unsigned r = u + 0x7FFFu + ((u >> 16) & 1u);   // RNE
    return (unsigned short)(r >> 16);
}

__device__ __forceinline__ void gl2lds16(const unsigned short* g, unsigned short* l) {
    __builtin_amdgcn_global_load_lds(
        (const __attribute__((address_space(1))) unsigned int*)g,
        (__attribute__((address_space(3))) unsigned int*)l, 16, 0, 0);
}

// ---------------- fused pack: z = [x|h] -> bf16, W -> bf16 transposed ----------------
// blocks [0, 8192): pack_z. blocks [8192, 8192+2048): pack_w:
// one block = 64k x 256n tile of one gate.
//   stage: 16 iters, each wave reads ONE 1KB row (fully coalesced), converts, writes
//          bf16 to T[64][258] (258-stride: scalar-read banks spread ~4-way max).
//   write: 8 iters; 8 threads cover one n-row's 64 k (128B contiguous per 8 lanes).
#define NZ_BLOCKS 8192
#define NW_BLOCKS 2048
__global__ __launch_bounds__(256) void pack_all(
    const float* __restrict__ x, const float* __restrict__ h,
    const float* __restrict__ Wf, const float* __restrict__ Wi,
    const float* __restrict__ Wc, const float* __restrict__ Wo,
    unsigned short* __restrict__ zA, unsigned short* __restrict__ WB) {
    __shared__ unsigned short T[64][258];
    int t = threadIdx.x;
    int b = blockIdx.x;
    if (b < NZ_BLOCKS) {
        int ch  = b * 256 + t;              // 8-elem chunks, 512/row
        int m   = ch >> 9;
        int pos = (ch & 511) * 8;
        const float* src = (pos < DIN) ? (x + (size_t)m * DIN + pos)
                                       : (h + (size_t)m * UNITS + (pos - DIN));
        float4 v0 = *(const float4*)(src);
        float4 v1 = *(const float4*)(src + 4);
        s8v o;
        o[0]=f2bf(v0.x); o[1]=f2bf(v0.y); o[2]=f2bf(v0.z); o[3]=f2bf(v0.w);
        o[4]=f2bf(v1.x); o[5]=f2bf(v1.y); o[6]=f2bf(v1.z); o[7]=f2bf(v1.w);
        *(s8v*)(zA + (size_t)ch * 8) = o;
        return;
    }
    int bb  = b - NZ_BLOCKS;
    int g   = bb >> 9;            // 512 tiles per gate
    int rem = bb & 511;
    int kt  = rem & 63;           // 64 k-tiles
    int nt  = rem >> 6;           // 8 n-tiles
    const float* Wg = (g == 0) ? Wf : (g == 1) ? Wi : (g == 2) ? Wc : Wo;
    int k0 = kt * 64, n0 = nt * 256;
    const int wv = t >> 6, l = t & 63;
    #pragma unroll
    for (int i = 0; i < 16; ++i) {
        int r = i * 4 + wv;                  // one row per wave per iter
        int c = l * 4;
        float4 v = *(const float4*)(Wg + (size_t)(k0 + r) * UNITS + n0 + c);
        T[r][c+0] = f2bf(v.x); T[r][c+1] = f2bf(v.y);
        T[r][c+2] = f2bf(v.z); T[r][c+3] = f2bf(v.w);
    }
    __syncthreads();
    #pragma unroll
    for (int it = 0; it < 8; ++it) {
        int s  = it * 256 + t;
        int ul = s >> 3;                     // n-row 0..255
        int kl = (s & 7) * 8;                // k chunk
        s8v o;
        #pragma unroll
        for (int j = 0; j < 8; ++j) o[j] = (short)T[kl + j][ul];
        *(s8v*)(WB + (size_t)(g * UNITS + n0 + ul) * KDIM + k0 + kl) = o;
    }
}

// ---------------- 256^2-tile 8-wave phase-pipelined GEMM + LSTM epilogue ----------------
// LDS per (buf,kh,matrix) region: 128 lines x 128 B; line L holds rows {2L,2L+1}.
// slog = (row&1)*4 + chunk; physical slot = slog ^ (L&7) -> conflict-free b128 reads.
// Staging dest linear (global_load_lds); inverse swizzle on global source (both-sides).
// lgkmcnt(3): B-frags + a[0] landed -> first MFMAs issue while remaining A-frags
// drain (compiler inserts its own finer waits for a[1..3]).
__global__ __launch_bounds__(512, 2) void lstm_gemm(
    const unsigned short* __restrict__ zA,   // 4096 x 4096 bf16
    const unsigned short* __restrict__ WB,   // 8192 x 4096 bf16, row n = g*2048+u
    const float* __restrict__ cin,
    const float* __restrict__ bfp, const float* __restrict__ bip,
    const float* __restrict__ bcp, const float* __restrict__ bop,
    float* __restrict__ out) {
    extern __shared__ unsigned short SMu[];   // 131072 B

    const int t    = threadIdx.x;
    const int lane = t & 63;
    const int wave = t >> 6;       // 0..7
    const int wm   = wave >> 2;    // 0..1  (m half)
    const int wn   = wave & 3;     // 0..3  (gate)
    const int fr   = lane & 15;
    const int q    = lane >> 4;

    // XCD-aware bijective swizzle (512 wgs, 8 XCDs, m-fast within XCD)
    int bid = blockIdx.x;
    int wg  = (bid & 7) * 64 + (bid >> 3);
    const int m0 = (wg & 15) * BM;
    const int u0 = (wg >> 4) * 64;

    // ---- staging: slots s = t and t+512 per region; slot -> (line, phys slot) ----
    const int L    = t >> 3;
    const int p    = t & 7;
    const int slog = p ^ (L & 7);
    const int rr   = 2 * L + (slog >> 2);    // row 0..127
    const int ch   = slog & 3;               // 8-bf16 chunk within kh-half
    const unsigned short* gA0 = zA + (size_t)(m0 + rr) * KDIM + ch * 8;
    const unsigned short* gB0 = WB + (size_t)((rr >> 6) * UNITS + u0 + (rr & 63)) * KDIM + ch * 8;
    const int dst0 = t * 8;                  // ushort offsets, linear
    const int dst1 = (t + 512) * 8;

    // ---- fragment read offsets (ushorts) ----
    const int fh      = fr >> 1;
    const int laneoff = fh * 64 + ((((fr & 1) << 2) | q) ^ fh) * 8;
    const int aoff = wm * 4096 + laneoff;            // + (mq*4+ii)*512 + kh*8192 + buf*32768
    const int boff = 16384 + wn * 2048 + laneoff;    // + jj*512       + kh*8192 + buf*32768

    f4v acc[8][4];
    #pragma unroll
    for (int i = 0; i < 8; ++i)
        #pragma unroll
        for (int j = 0; j < 4; ++j) acc[i][j] = (f4v){0.f, 0.f, 0.f, 0.f};

#define STAGE_A(khv) do { \
    gl2lds16(gA0 + ko + (khv)*32, nxt + (khv)*8192 + dst0); \
    gl2lds16(gA0 + (size_t)128*KDIM + ko + (khv)*32, nxt + (khv)*8192 + dst1); } while(0)
#define STAGE_B(khv) do { \
    gl2lds16(gB0 + ko + (khv)*32, nxt + 16384 + (khv)*8192 + dst0); \
    gl2lds16(gB0 + (size_t)2*UNITS*KDIM + ko + (khv)*32, nxt + 16384 + (khv)*8192 + dst1); } while(0)
#define LDB4(khv) { _Pragma("unroll") for (int jj = 0; jj < 4; ++jj) \
    b[jj] = *(const s8v*)(cur + boff + (khv)*8192 + jj*512); }
#define LDA4(khv, mqv) { _Pragma("unroll") for (int ii = 0; ii < 4; ++ii) \
    a[ii] = *(const s8v*)(cur + aoff + (khv)*8192 + ((mqv)*4+ii)*512); }
#define MFMA16(mqv) { _Pragma("unroll") for (int ii = 0; ii < 4; ++ii) \
    _Pragma("unroll") for (int jj = 0; jj < 4; ++jj) \
    acc[(mqv)*4+ii][jj] = __builtin_amdgcn_mfma_f32_16x16x32_bf16(a[ii], b[jj], acc[(mqv)*4+ii][jj], 0, 0, 0); }
#define BAR()  __builtin_amdgcn_s_barrier()
#define LGK3() do { asm volatile("s_waitcnt lgkmcnt(3)" ::: "memory"); \
                    __builtin_amdgcn_sched_barrier(0); } while(0)
#define VM(n)  asm volatile("s_waitcnt vmcnt(" #n ")" ::: "memory")

    // ---- prologue: stage tile 0 into buf 0 (issue order = consume order) ----
    {
        unsigned short* nxt = SMu;
        const int ko = 0;
        STAGE_A(0); STAGE_B(0);
        __builtin_amdgcn_sched_barrier(0);
        STAGE_A(1); STAGE_B(1);
        __builtin_amdgcn_sched_barrier(0);
    }
    VM(4);          // A_k0(0), B_k0(0) landed; k1 halves stay in flight
    BAR();

    s8v a[4], b[4];
    #pragma unroll 1
    for (int kt = 0; kt < 63; ++kt) {
        const unsigned short* cur = SMu + ((kt & 1) << 15);
        unsigned short* nxt = SMu + (((kt & 1) ^ 1) << 15);
        const int ko = (kt + 1) * BK;
        // phase 0: (kh0, mq0) | stage A_k0(t+1)
        LDB4(0); LDA4(0, 0); STAGE_A(0);
        BAR(); LGK3();
        __builtin_amdgcn_s_setprio(1); MFMA16(0); __builtin_amdgcn_s_setprio(0);
        BAR();
        // phase 1: (kh0, mq1) | stage B_k0(t+1) | vmcnt(4): k1(t) halves landed
        LDA4(0, 1); STAGE_B(0);
        BAR(); LGK3();
        __builtin_amdgcn_s_setprio(1); MFMA16(1); __builtin_amdgcn_s_setprio(0);
        VM(4);
        BAR();
        // phase 2: (kh1, mq0) | stage A_k1(t+1)
        LDB4(1); LDA4(1, 0); STAGE_A(1);
        BAR(); LGK3();
        __builtin_amdgcn_s_setprio(1); MFMA16(0); __builtin_amdgcn_s_setprio(0);
        BAR();
        // phase 3: (kh1, mq1) | stage B_k1(t+1) | vmcnt(4): k0(t+1) halves landed
        LDA4(1, 1); STAGE_B(1);
        BAR(); LGK3();
        __builtin_amdgcn_s_setprio(1); MFMA16(1); __builtin_amdgcn_s_setprio(0);
        VM(4);
        BAR();
    }
    // ---- tail: tile 63, no staging ----
    {
        const unsigned short* cur = SMu + ((63 & 1) << 15);
        LDB4(0); LDA4(0, 0);
        BAR(); LGK3();
        __builtin_amdgcn_s_setprio(1); MFMA16(0); __builtin_amdgcn_s_setprio(0);
        BAR();
        LDA4(0, 1);
        BAR(); LGK3();
        __builtin_amdgcn_s_setprio(1); MFMA16(1); __builtin_amdgcn_s_setprio(0);
        VM(0);
        BAR();
        LDB4(1); LDA4(1, 0);
        BAR(); LGK3();
        __builtin_amdgcn_s_setprio(1); MFMA16(0); __builtin_amdgcn_s_setprio(0);
        BAR();
        LDA4(1, 1);
        BAR(); LGK3();
        __builtin_amdgcn_s_setprio(1); MFMA16(1); __builtin_amdgcn_s_setprio(0);
        BAR();
    }

    // ---- fused epilogue: 4 chunks of 64 m-rows through padded f32 LDS ----
    // chk loop FULLY unrolled: all acc indices compile-time (rule #20).
    float* E = (float*)SMu;
    const int EW = 260;
    const int du = lane;
    float bF = bfp[u0 + du], bI = bip[u0 + du], bG = bcp[u0 + du], bO = bop[u0 + du];
    float* outh = out;
    float* outc = out + (size_t)B_DIM * UNITS;
    #pragma unroll
    for (int chk = 0; chk < 4; ++chk) {
        if (wm == (chk >> 1)) {
            const int i0 = (chk & 1) * 4;
            #pragma unroll
            for (int ii = 0; ii < 4; ++ii)
                #pragma unroll
                for (int j = 0; j < 4; ++j) {
                    int col = wn * 64 + j * 16 + fr;
                    #pragma unroll
                    for (int pp = 0; pp < 4; ++pp)
                        E[(ii * 16 + q * 4 + pp) * EW + col] = acc[i0 + ii][j][pp];
                }
        }
        __syncthreads();
        #pragma unroll
        for (int v = 0; v < 8; ++v) {
            int rloc = v * 8 + wave;
            float F = E[rloc * EW +       du] + bF;
            float I = E[rloc * EW +  64 + du] + bI;
            float G = E[rloc * EW + 128 + du] + bG;
            float O = E[rloc * EW + 192 + du] + bO;
            int m = m0 + chk * 64 + rloc;
            size_t off = (size_t)m * UNITS + u0 + du;
            float cv = cin[off];
            float fg = 1.f / (1.f + __expf(-F));
            float ig = 1.f / (1.f + __expf(-I));
            float gg = 1.f - 2.f / (1.f + __expf(2.f * G));   // tanh, inf-safe
            float og = 1.f / (1.f + __expf(-O));
            float nc = fg * cv + ig * gg;
            float nh = og * (1.f - 2.f / (1.f + __expf(2.f * nc)));
            outc[off] = nc;
            outh[off] = nh;
        }
        __syncthreads();
    }
}

extern "C" void kernel_launch(void* const* d_in, const int* in_sizes, int n_in,
                              void* d_out, int out_size, void* d_ws, size_t ws_size,
                              hipStream_t stream) {
    const float* x  = (const float*)d_in[0];
    const float* h  = (const float*)d_in[1];
    const float* c  = (const float*)d_in[2];
    const float* Wf = (const float*)d_in[3];
    const float* bf = (const float*)d_in[4];
    const float* Wi = (const float*)d_in[5];
    const float* bi = (const float*)d_in[6];
    const float* Wc = (const float*)d_in[7];
    const float* bc = (const float*)d_in[8];
    const float* Wo = (const float*)d_in[9];
    const float* bo = (const float*)d_in[10];

    unsigned short* zA = (unsigned short*)d_ws;                 // 32 MB
    unsigned short* WB = zA + (size_t)B_DIM * KDIM;             // 64 MB

    hipFuncSetAttribute(reinterpret_cast<const void*>(lstm_gemm),
                        hipFuncAttributeMaxDynamicSharedMemorySize, 131072);

    pack_all<<<NZ_BLOCKS + NW_BLOCKS, 256, 0, stream>>>(x, h, Wf, Wi, Wc, Wo, zA, WB);
    lstm_gemm<<<dim3(512), 512, 131072, stream>>>(
        zA, WB, c, bf, bi, bc, bo, (float*)d_out);
}